// Round 1
// baseline (307.033 us; speedup 1.0000x reference)
//
#include <hip/hip_runtime.h>
#include <hip/hip_fp16.h>

#define N_NODES  50000
#define N_EDGES  640000
#define N_GRAPHS 500
static constexpr float BN_EPS = 1e-5f;
#define SCAN_NB ((N_NODES + 255) / 256)   // 196 blocks
static constexpr float FIX = 16777216.0f;       // 2^24
static constexpr float FIXINV = 5.9604644775390625e-8f;  // 2^-24
static constexpr float Q16 = 65535.0f;
static constexpr float Q16INV = 1.0f / 65535.0f;

// csr entry: (src<<16) | round(norm*65535). src<50000<2^16; norm<1.
__device__ __forceinline__ float dec_nm(unsigned e) {
    return (float)(e & 0xFFFFu) * Q16INV;
}

// ---------------------------------------------------------------------------
// Packed degree/count: one 64-bit atomic per edge; old value -> seq[] rank.
__global__ void k_degcnt(const int* __restrict__ dst, const float* __restrict__ w,
                         unsigned long long* __restrict__ packed,
                         int* __restrict__ seq, int E) {
    int i = blockIdx.x * blockDim.x + threadIdx.x;
    if (i < E) {
        int d = dst[i];
        unsigned uf = (unsigned)(w[i] * FIX + 0.5f);
        unsigned long long old =
            atomicAdd(&packed[d], (1ULL << 32) | (unsigned long long)uf);
        seq[i] = (int)(old >> 32);
    }
}

// --- 3-phase hierarchical exclusive scan of counts (packed hi32) -> offs ---
// Also computes per-graph node ranges (goffs) in blocks 0/1 — overlapped with
// the other 194 blocks' scan work; removes the redundant binary search from
// all 500 k_poolfinal blocks.
__global__ void k_scan1(const unsigned long long* __restrict__ packed,
                        int* __restrict__ bsum,
                        const int* __restrict__ batch, int* __restrict__ goffs,
                        int n) {
    __shared__ int red[256];
    int i = blockIdx.x * 256 + threadIdx.x;
    red[threadIdx.x] = (i < n) ? (int)(packed[i] >> 32) : 0;
    __syncthreads();
    for (int off = 128; off > 0; off >>= 1) {
        if (threadIdx.x < off) red[threadIdx.x] += red[threadIdx.x + off];
        __syncthreads();
    }
    if (threadIdx.x == 0) bsum[blockIdx.x] = red[0];
    // graph range precompute: goffs[g] = lower_bound(batch, g), goffs[G] = n
    if (i <= N_GRAPHS) {
        int lo = 0, hi = n;
        while (lo < hi) { int m = (lo + hi) >> 1; if (batch[m] < i) lo = m + 1; else hi = m; }
        goffs[i] = lo;
    }
}

// scan2 + bnprep fused (both tiny single-block jobs — saves one launch).
__global__ void k_scan2_bnprep(
    const int* __restrict__ bsum, int* __restrict__ bpre, int nb,
    const float* W1,
    const float* b1, const float* g1, const float* be1, const float* m1, const float* v1,
    const float* b2, const float* g2, const float* be2, const float* m2, const float* v2,
    const float* b3, const float* g3, const float* be3, const float* m3, const float* v3,
    float* kA1, float* kB1, float* kA2, float* kB2, float* kA3, float* kB3) {
    __shared__ int part[256];
    int t = threadIdx.x;
    if (t < 256) {
        part[t] = (t < nb) ? bsum[t] : 0;
    }
    __syncthreads();
    for (int off = 1; off < 256; off <<= 1) {
        int v = (t < 256 && t >= off) ? part[t - off] : 0;
        __syncthreads();
        if (t < 256) part[t] += v;
        __syncthreads();
    }
    if (t < nb) bpre[t] = (t == 0) ? 0 : part[t - 1];
    // bnprep (independent of scan)
    if (t < 64) {
        float s = g1[t] * rsqrtf(v1[t] + BN_EPS);
        kA1[t] = W1[t] * s;
        kB1[t] = (b1[t] - m1[t]) * s + be1[t];
    } else if (t < 192) {
        int c = t - 64;
        float s = g2[c] * rsqrtf(v2[c] + BN_EPS);
        kA2[c] = s; kB2[c] = (b2[c] - m2[c]) * s + be2[c];
    } else if (t < 320) {
        int c = t - 192;
        float s = g3[c] * rsqrtf(v3[c] + BN_EPS);
        kA3[c] = s; kB3[c] = (b3[c] - m3[c]) * s + be3[c];
    }
}

// scan3 + dinv + aggx-selfterm fused (same N-grid).
__global__ void k_scan3(const unsigned long long* __restrict__ packed,
                        const int* __restrict__ bpre, int* __restrict__ offs,
                        float* __restrict__ dinv,
                        const float* __restrict__ x, float* __restrict__ aggx,
                        int n) {
    __shared__ int part[256];
    int i = blockIdx.x * 256 + threadIdx.x;
    int t = threadIdx.x;
    unsigned long long pk = (i < n) ? packed[i] : 0ULL;
    int v = (int)(pk >> 32);
    part[t] = v;
    __syncthreads();
    for (int off = 1; off < 256; off <<= 1) {
        int u = (t >= off) ? part[t - off] : 0;
        __syncthreads();
        part[t] += u;
        __syncthreads();
    }
    int excl = bpre[blockIdx.x] + part[t] - v;
    if (i < n) {
        offs[i] = excl;
        float wdeg = (float)(unsigned)(pk & 0xFFFFFFFFu) * FIXINV;
        float di = rsqrtf(wdeg + 1.0f);
        dinv[i] = di;
        // layer-1 self-loop term; edge contributions atomically added by k_fill
        aggx[i] = x[i] * di * di;
    }
    if (i == n - 1) offs[n] = N_EDGES;
}

// Atomic-free CSR fill: pos = offs[dst] + seq[e]. 4-byte packed entry.
// Fused layer-1 scalar aggregation: edge-parallel fp32 atomics into aggx
// (replaces the latency-bound 196-block k_aggx; uses unquantized norm).
__global__ void k_fill(const int* __restrict__ src, const int* __restrict__ dst,
                       const float* __restrict__ w, const float* __restrict__ x,
                       const float* __restrict__ dinv,
                       const int* __restrict__ offs, const int* __restrict__ seq,
                       unsigned* __restrict__ csr, float* __restrict__ aggx, int E) {
    int e = blockIdx.x * blockDim.x + threadIdx.x;
    if (e < E) {
        int s = src[e], d = dst[e];
        int pos = offs[d] + seq[e];
        float nm = dinv[s] * w[e] * dinv[d];
        unsigned q = (unsigned)(nm * Q16 + 0.5f);
        q = (q > 65535u) ? 65535u : q;
        csr[pos] = ((unsigned)s << 16) | q;
        atomicAdd(&aggx[d], x[s] * nm);
    }
}

// ---------------------------------------------------------------------------
// Fused layer-1-matmul + layer-2 aggregation. 16 threads/node, 4 ch each.
// 8-edge unroll (r22: gather2F loads are lighter per edge than gatherS16's —
// deeper MLP should still pay here).
__global__ void k_gather2F(const int* __restrict__ offs, const unsigned* __restrict__ csr,
                           const float* __restrict__ aggx, const float* __restrict__ dinv,
                           const float* __restrict__ kA1, const float* __restrict__ kB1,
                           float* __restrict__ agg2, int n) {
    int gid = blockIdx.x * blockDim.x + threadIdx.x;
    int node = gid >> 4;
    if (node >= n) return;
    int c4 = (gid & 15) * 4;
    float4 wa = *(const float4*)(kA1 + c4);
    float4 wb = *(const float4*)(kB1 + c4);
    float4 acc = {0.f, 0.f, 0.f, 0.f};
    int e0 = offs[node], e1 = offs[node + 1];
    int j = e0;
#define G2F_ACC(av, nmv) { \
        acc.x += nmv * fmaxf(av * wa.x + wb.x, 0.f); \
        acc.y += nmv * fmaxf(av * wa.y + wb.y, 0.f); \
        acc.z += nmv * fmaxf(av * wa.z + wb.z, 0.f); \
        acc.w += nmv * fmaxf(av * wa.w + wb.w, 0.f); }
    for (; j + 7 < e1; j += 8) {
        unsigned e_0 = csr[j];
        unsigned e_1 = csr[j + 1];
        unsigned e_2 = csr[j + 2];
        unsigned e_3 = csr[j + 3];
        unsigned e_4 = csr[j + 4];
        unsigned e_5 = csr[j + 5];
        unsigned e_6 = csr[j + 6];
        unsigned e_7 = csr[j + 7];
        float a0 = aggx[e_0 >> 16];
        float a1 = aggx[e_1 >> 16];
        float a2 = aggx[e_2 >> 16];
        float a3 = aggx[e_3 >> 16];
        float a4 = aggx[e_4 >> 16];
        float a5 = aggx[e_5 >> 16];
        float a6 = aggx[e_6 >> 16];
        float a7 = aggx[e_7 >> 16];
        G2F_ACC(a0, dec_nm(e_0)); G2F_ACC(a1, dec_nm(e_1));
        G2F_ACC(a2, dec_nm(e_2)); G2F_ACC(a3, dec_nm(e_3));
        G2F_ACC(a4, dec_nm(e_4)); G2F_ACC(a5, dec_nm(e_5));
        G2F_ACC(a6, dec_nm(e_6)); G2F_ACC(a7, dec_nm(e_7));
    }
    for (; j < e1; ++j) {
        unsigned e = csr[j];
        float a = aggx[e >> 16];
        G2F_ACC(a, dec_nm(e));
    }
    {
        float di = dinv[node];
        float d2 = di * di;
        float a = aggx[node];
        G2F_ACC(a, d2);
    }
#undef G2F_ACC
    *(float4*)(agg2 + (size_t)node * 64 + c4) = acc;
}

// ---------------------------------------------------------------------------
// Channel-sliced gather (layer 3) from the FP16 layer-2 output (sliced-16):
// slice table 1.6MB (L2-resident), 4 thr/node, 8B/thread, fp32 accumulation,
// 8-edge unroll.
__global__ void k_gatherS16(const int* __restrict__ offs, const unsigned* __restrict__ csr,
                            const __half* __restrict__ Hh, const float* __restrict__ dinv,
                            float* __restrict__ aggs, int n) {
    int slice = blockIdx.x & 7;
    int node = (blockIdx.x >> 3) * 64 + threadIdx.x / 4;
    if (node >= n) return;
    int cq = (threadIdx.x % 4) * 4;
    const __half* Hb = Hh + (size_t)slice * ((size_t)n * 16);
    float4 acc = {0.f, 0.f, 0.f, 0.f};
    int e0 = offs[node], e1 = offs[node + 1];
    int j = e0;
#define GS16_LOAD(ev, rawv) uint2 rawv = *(const uint2*)(Hb + (size_t)((ev) >> 16) * 16 + cq)
#define GS16_ACC(rawv, nmv) { \
        __half2 p0 = *(__half2*)&rawv.x; \
        __half2 p1 = *(__half2*)&rawv.y; \
        float2 f0 = __half22float2(p0); \
        float2 f1 = __half22float2(p1); \
        acc.x += f0.x * nmv; acc.y += f0.y * nmv; \
        acc.z += f1.x * nmv; acc.w += f1.y * nmv; }
    for (; j + 7 < e1; j += 8) {
        unsigned e_0 = csr[j];
        unsigned e_1 = csr[j + 1];
        unsigned e_2 = csr[j + 2];
        unsigned e_3 = csr[j + 3];
        unsigned e_4 = csr[j + 4];
        unsigned e_5 = csr[j + 5];
        unsigned e_6 = csr[j + 6];
        unsigned e_7 = csr[j + 7];
        GS16_LOAD(e_0, r0); GS16_LOAD(e_1, r1); GS16_LOAD(e_2, r2); GS16_LOAD(e_3, r3);
        GS16_LOAD(e_4, r4); GS16_LOAD(e_5, r5); GS16_LOAD(e_6, r6); GS16_LOAD(e_7, r7);
        GS16_ACC(r0, dec_nm(e_0)); GS16_ACC(r1, dec_nm(e_1));
        GS16_ACC(r2, dec_nm(e_2)); GS16_ACC(r3, dec_nm(e_3));
        GS16_ACC(r4, dec_nm(e_4)); GS16_ACC(r5, dec_nm(e_5));
        GS16_ACC(r6, dec_nm(e_6)); GS16_ACC(r7, dec_nm(e_7));
    }
    for (; j < e1; ++j) {
        unsigned e = csr[j];
        GS16_LOAD(e, rr);
        GS16_ACC(rr, dec_nm(e));
    }
    {
        float di = dinv[node];
        float d2 = di * di;
        GS16_LOAD((unsigned)node << 16, rs);
        GS16_ACC(rs, d2);
    }
#undef GS16_LOAD
#undef GS16_ACC
    *(float4*)(aggs + (size_t)slice * ((size_t)n * 16) + (size_t)node * 16 + cq) = acc;
}

// ---------------------------------------------------------------------------
// Register-tiled matmul: 32 nodes/block, x-tile AND W staged in LDS.
// k4/p loops pinned rolled (#pragma unroll 1) — r6/r8 spilled at 256 VGPR.
// Sliced-16 slot layout. MODE 0 (layer 2): write fp16 table only.
// MODE 1 (layer 3): residual from fp16 table; write fp32 IN-PLACE into Xs.
template <int K, int S, int MODE>
__global__ __launch_bounds__(256) void k_mmT(
    const float* __restrict__ Xs, const float* __restrict__ W,
    const float* __restrict__ kA, const float* __restrict__ kB,
    const __half* __restrict__ resh, float* __restrict__ outs,
    __half* __restrict__ outh, int n) {
    constexpr int CS = K / S;
    constexpr int KP = K + 4;
    constexpr int KH = 64;
    constexpr int NPASS = K / KH;
    __shared__ float xl[32 * KP];
    __shared__ float wl[KH * 128];
    int base = blockIdx.x * 32;
    int tid = threadIdx.x;
    constexpr int TOT4 = 32 * K / 4;
    constexpr int SL4 = 32 * CS / 4;
    for (int i = tid; i < TOT4; i += 256) {
        int slice = i / SL4;
        int rem = i - slice * SL4;
        int nl = rem / (CS / 4);
        int off4 = (rem % (CS / 4)) * 4;
        int node = base + nl;
        float4 v = {0.f, 0.f, 0.f, 0.f};
        if (node < n)
            v = *(const float4*)(Xs + (size_t)slice * ((size_t)n * CS) + (size_t)node * CS + off4);
        *(float4*)(&xl[nl * KP + slice * CS + off4]) = v;
    }

    int ct = tid & 31;
    int ng = tid >> 5;
    int c4 = ct * 4;
    float4 acc[4];
#pragma unroll
    for (int i = 0; i < 4; ++i) acc[i] = make_float4(0.f, 0.f, 0.f, 0.f);

#pragma unroll 1
    for (int p = 0; p < NPASS; ++p) {
        if (p > 0) __syncthreads();
        {
            const float4* Wsrc = (const float4*)(W + (size_t)p * KH * 128);
            float4* wl4 = (float4*)wl;
#pragma unroll 1
            for (int i = tid; i < KH * 32; i += 256) wl4[i] = Wsrc[i];
        }
        __syncthreads();

#pragma unroll 1
        for (int k4 = 0; k4 < KH / 4; ++k4) {
            float4 wv0 = *(const float4*)(&wl[(k4 * 4 + 0) * 128 + c4]);
            float4 wv1 = *(const float4*)(&wl[(k4 * 4 + 1) * 128 + c4]);
            float4 wv2 = *(const float4*)(&wl[(k4 * 4 + 2) * 128 + c4]);
            float4 wv3 = *(const float4*)(&wl[(k4 * 4 + 3) * 128 + c4]);
#pragma unroll
            for (int i = 0; i < 4; ++i) {
                float4 xv = *(const float4*)(&xl[(ng * 4 + i) * KP + p * KH + k4 * 4]);
                acc[i].x += xv.x * wv0.x; acc[i].y += xv.x * wv0.y;
                acc[i].z += xv.x * wv0.z; acc[i].w += xv.x * wv0.w;
                acc[i].x += xv.y * wv1.x; acc[i].y += xv.y * wv1.y;
                acc[i].z += xv.y * wv1.z; acc[i].w += xv.y * wv1.w;
                acc[i].x += xv.z * wv2.x; acc[i].y += xv.z * wv2.y;
                acc[i].z += xv.z * wv2.z; acc[i].w += xv.z * wv2.w;
                acc[i].x += xv.w * wv3.x; acc[i].y += xv.w * wv3.y;
                acc[i].z += xv.w * wv3.z; acc[i].w += xv.w * wv3.w;
            }
        }
    }

    float4 ka = *(const float4*)(kA + c4);
    float4 kb = *(const float4*)(kB + c4);
#pragma unroll
    for (int i = 0; i < 4; ++i) {
        int node = base + ng * 4 + i;
        if (node >= n) continue;
        float4 a = acc[i];
        float4 v;
        v.x = fmaxf(a.x * ka.x + kb.x, 0.f);
        v.y = fmaxf(a.y * ka.y + kb.y, 0.f);
        v.z = fmaxf(a.z * ka.z + kb.z, 0.f);
        v.w = fmaxf(a.w * ka.w + kb.w, 0.f);
        size_t slot = (size_t)(c4 >> 4) * ((size_t)n * 16) + (size_t)node * 16 + (c4 & 15);
        if (MODE == 0) {
            __half2 h01 = __floats2half2_rn(v.x, v.y);
            __half2 h23 = __floats2half2_rn(v.z, v.w);
            uint2 r;
            r.x = *(unsigned*)&h01;
            r.y = *(unsigned*)&h23;
            *(uint2*)(outh + slot) = r;
        } else {
            uint2 rr = *(const uint2*)(resh + slot);
            __half2 p0 = *(__half2*)&rr.x;
            __half2 p1 = *(__half2*)&rr.y;
            float2 f0 = __half22float2(p0);
            float2 f1 = __half22float2(p1);
            v.x += f0.x; v.y += f0.y; v.z += f1.x; v.w += f1.y;
            *(float4*)(outs + slot) = v;
        }
    }
}

// ---------------------------------------------------------------------------
// Per-graph mean-pool + final linear. Graph ranges precomputed (goffs).
// 1024 threads: thread t owns channel t&127, sub-lane t>>7 (8-way node split).
__global__ __launch_bounds__(1024) void k_poolfinal(
    const float* __restrict__ Hs, const int* __restrict__ goffs,
    const float* __restrict__ Wf, const float* __restrict__ bf,
    float* __restrict__ out, int n) {
    int g = blockIdx.x;
    int t = threadIdx.x;
    int ch = t & 127;
    int sub = t >> 7;           // 0..7
    int start = goffs[g];
    int end = goffs[g + 1];

    const float* base = Hs + (size_t)(ch >> 4) * ((size_t)n * 16) + (ch & 15);
    float acc = 0.f;
    for (int i = start + sub; i < end; i += 8) acc += base[(size_t)i * 16];

    __shared__ float red[1024];
    red[t] = acc;
    __syncthreads();
    for (int s = 512; s >= 128; s >>= 1) {
        if (t < s) red[t] += red[t + s];
        __syncthreads();
    }
    if (t < 128) red[t] *= Wf[t];
    __syncthreads();
    for (int s = 64; s > 0; s >>= 1) {
        if (t < s) red[t] += red[t + s];
        __syncthreads();
    }
    if (t == 0) out[g] = red[0] / fmaxf((float)(end - start), 1.f) + bf[0];
}

// ---------------------------------------------------------------------------
extern "C" void kernel_launch(void* const* d_in, const int* in_sizes, int n_in,
                              void* d_out, int out_size, void* d_ws, size_t ws_size,
                              hipStream_t stream) {
    const float* x     = (const float*)d_in[0];
    const int*   ei    = (const int*)d_in[1];
    const int*   src   = ei;
    const int*   dst   = ei + N_EDGES;
    const float* w     = (const float*)d_in[2];
    const int*   batch = (const int*)d_in[3];
    const float* W1 = (const float*)d_in[4];
    const float* b1 = (const float*)d_in[5];
    const float* W2 = (const float*)d_in[6];
    const float* b2 = (const float*)d_in[7];
    const float* W3 = (const float*)d_in[8];
    const float* b3 = (const float*)d_in[9];
    const float* Wf = (const float*)d_in[10];
    const float* bf = (const float*)d_in[11];
    const float* g1 = (const float*)d_in[12];
    const float* be1 = (const float*)d_in[13];
    const float* m1 = (const float*)d_in[14];
    const float* v1 = (const float*)d_in[15];
    const float* g2 = (const float*)d_in[16];
    const float* be2 = (const float*)d_in[17];
    const float* m2 = (const float*)d_in[18];
    const float* v2 = (const float*)d_in[19];
    const float* g3 = (const float*)d_in[20];
    const float* be3 = (const float*)d_in[21];
    const float* m3 = (const float*)d_in[22];
    const float* v3 = (const float*)d_in[23];

    float* out = (float*)d_out;

    // Workspace layout
    float* ws    = (float*)d_ws;
    float* buf2  = ws;                                    // N*128 fp32: agg2 then agg3s
    float* agg2  = buf2;                                  //   (mmT128 writes out3 in-place)
    unsigned* csr = (unsigned*)(buf2 + (size_t)N_NODES * 128); // E uint
    unsigned long long* packed = (unsigned long long*)(csr + N_EDGES); // N ull
    int*   seq   = (int*)(packed + N_NODES);              // E
    float* dinv  = (float*)(seq + N_EDGES);               // N
    float* aggx  = dinv + N_NODES;                        // N
    float* kA1   = aggx + N_NODES;                        // 64
    float* kB1   = kA1 + 64;                              // 64
    float* kA2   = kB1 + 64;                              // 128
    float* kB2   = kA2 + 128;                             // 128
    float* kA3   = kB2 + 128;                             // 128
    float* kB3   = kA3 + 128;                             // 128
    int*   offs  = (int*)(kB3 + 128);                     // N+1
    int*   bsum  = offs + N_NODES + 1;                    // SCAN_NB
    int*   bpre  = bsum + SCAN_NB;                        // SCAN_NB
    int*   goffs = bpre + SCAN_NB;                        // G+1 (+pad)
    __half* out2h = (__half*)(goffs + 505);               // N*128 fp16 (12.8 MB)

    const int BS = 256;
    auto nb = [](long n) { return (int)((n + 255) / 256); };

    hipMemsetAsync(packed, 0, N_NODES * sizeof(unsigned long long), stream);

    // --- CSR build + degree norm (+goffs precompute overlapped in scan1) ---
    k_degcnt<<<nb(N_EDGES), BS, 0, stream>>>(dst, w, packed, seq, N_EDGES);
    k_scan1<<<SCAN_NB, 256, 0, stream>>>(packed, bsum, batch, goffs, N_NODES);
    k_scan2_bnprep<<<1, 320, 0, stream>>>(bsum, bpre, SCAN_NB,
                                          W1, b1, g1, be1, m1, v1, b2, g2, be2, m2, v2,
                                          b3, g3, be3, m3, v3,
                                          kA1, kB1, kA2, kB2, kA3, kB3);
    k_scan3<<<SCAN_NB, 256, 0, stream>>>(packed, bpre, offs, dinv, x, aggx, N_NODES);
    // fill fuses layer-1 edge aggregation (atomics into aggx)
    k_fill<<<nb(N_EDGES), BS, 0, stream>>>(src, dst, w, x, dinv, offs, seq, csr, aggx, N_EDGES);

    // --- Layer 2: fused L1-matmul + aggregate (8-edge unroll), then matmul -> fp16 ---
    k_gather2F<<<nb((long)N_NODES * 16), BS, 0, stream>>>(
        offs, csr, aggx, dinv, kA1, kB1, agg2, N_NODES);
    k_mmT<64, 1, 0><<<(N_NODES + 31) / 32, BS, 0, stream>>>(
        agg2, W2, kA2, kB2, nullptr, nullptr, out2h, N_NODES);

    // --- Layer 3: sliced aggregate from fp16 table, matmul + relu + fp16 res ---
    k_gatherS16<<<8 * ((N_NODES + 63) / 64), BS, 0, stream>>>(
        offs, csr, out2h, dinv, buf2, N_NODES);
    k_mmT<128, 8, 1><<<(N_NODES + 31) / 32, BS, 0, stream>>>(
        buf2, W3, kA3, kB3, out2h, buf2, nullptr, N_NODES);

    // --- per-graph mean pool + final linear (1024-thread, 8-way node split) ---
    k_poolfinal<<<N_GRAPHS, 1024, 0, stream>>>(buf2, goffs, Wf, bf, out, N_NODES);
}

// Round 2
// 275.159 us; speedup vs baseline: 1.1158x; 1.1158x over previous
//
#include <hip/hip_runtime.h>
#include <hip/hip_fp16.h>

#define N_NODES  50000
#define N_EDGES  640000
#define N_GRAPHS 500
static constexpr float BN_EPS = 1e-5f;
#define SCAN_NB ((N_NODES + 255) / 256)   // 196 blocks
static constexpr float FIX = 16777216.0f;       // 2^24
static constexpr float FIXINV = 5.9604644775390625e-8f;  // 2^-24
static constexpr float Q16 = 65535.0f;
static constexpr float Q16INV = 1.0f / 65535.0f;

// csr entry: (src<<16) | round(norm*65535). src<50000<2^16; norm<1.
__device__ __forceinline__ float dec_nm(unsigned e) {
    return (float)(e & 0xFFFFu) * Q16INV;
}

// ---------------------------------------------------------------------------
// Packed degree/count: one 64-bit atomic per edge; old value -> seq[] rank.
__global__ void k_degcnt(const int* __restrict__ dst, const float* __restrict__ w,
                         unsigned long long* __restrict__ packed,
                         int* __restrict__ seq, int E) {
    int i = blockIdx.x * blockDim.x + threadIdx.x;
    if (i < E) {
        int d = dst[i];
        unsigned uf = (unsigned)(w[i] * FIX + 0.5f);
        unsigned long long old =
            atomicAdd(&packed[d], (1ULL << 32) | (unsigned long long)uf);
        seq[i] = (int)(old >> 32);
    }
}

// --- 3-phase hierarchical exclusive scan of counts (packed hi32) -> offs ---
// Blocks also compute per-graph node ranges (goffs) — overlapped with the
// other blocks' scan work; removes binary searches from the final kernel.
__global__ void k_scan1(const unsigned long long* __restrict__ packed,
                        int* __restrict__ bsum,
                        const int* __restrict__ batch, int* __restrict__ goffs,
                        int n) {
    __shared__ int red[256];
    int i = blockIdx.x * 256 + threadIdx.x;
    red[threadIdx.x] = (i < n) ? (int)(packed[i] >> 32) : 0;
    __syncthreads();
    for (int off = 128; off > 0; off >>= 1) {
        if (threadIdx.x < off) red[threadIdx.x] += red[threadIdx.x + off];
        __syncthreads();
    }
    if (threadIdx.x == 0) bsum[blockIdx.x] = red[0];
    // graph range precompute: goffs[g] = lower_bound(batch, g), goffs[G] = n
    if (i <= N_GRAPHS) {
        int lo = 0, hi = n;
        while (lo < hi) { int m = (lo + hi) >> 1; if (batch[m] < i) lo = m + 1; else hi = m; }
        goffs[i] = lo;
    }
}

// scan2 + bnprep fused (both tiny single-block jobs — saves one launch).
__global__ void k_scan2_bnprep(
    const int* __restrict__ bsum, int* __restrict__ bpre, int nb,
    const float* W1,
    const float* b1, const float* g1, const float* be1, const float* m1, const float* v1,
    const float* b2, const float* g2, const float* be2, const float* m2, const float* v2,
    const float* b3, const float* g3, const float* be3, const float* m3, const float* v3,
    float* kA1, float* kB1, float* kA2, float* kB2, float* kA3, float* kB3) {
    __shared__ int part[256];
    int t = threadIdx.x;
    if (t < 256) {
        part[t] = (t < nb) ? bsum[t] : 0;
    }
    __syncthreads();
    for (int off = 1; off < 256; off <<= 1) {
        int v = (t < 256 && t >= off) ? part[t - off] : 0;
        __syncthreads();
        if (t < 256) part[t] += v;
        __syncthreads();
    }
    if (t < nb) bpre[t] = (t == 0) ? 0 : part[t - 1];
    // bnprep (independent of scan)
    if (t < 64) {
        float s = g1[t] * rsqrtf(v1[t] + BN_EPS);
        kA1[t] = W1[t] * s;
        kB1[t] = (b1[t] - m1[t]) * s + be1[t];
    } else if (t < 192) {
        int c = t - 64;
        float s = g2[c] * rsqrtf(v2[c] + BN_EPS);
        kA2[c] = s; kB2[c] = (b2[c] - m2[c]) * s + be2[c];
    } else if (t < 320) {
        int c = t - 192;
        float s = g3[c] * rsqrtf(v3[c] + BN_EPS);
        kA3[c] = s; kB3[c] = (b3[c] - m3[c]) * s + be3[c];
    }
}

// scan3 + dinv fused (same N-grid).
__global__ void k_scan3(const unsigned long long* __restrict__ packed,
                        const int* __restrict__ bpre, int* __restrict__ offs,
                        float* __restrict__ dinv, int n) {
    __shared__ int part[256];
    int i = blockIdx.x * 256 + threadIdx.x;
    int t = threadIdx.x;
    unsigned long long pk = (i < n) ? packed[i] : 0ULL;
    int v = (int)(pk >> 32);
    part[t] = v;
    __syncthreads();
    for (int off = 1; off < 256; off <<= 1) {
        int u = (t >= off) ? part[t - off] : 0;
        __syncthreads();
        part[t] += u;
        __syncthreads();
    }
    int excl = bpre[blockIdx.x] + part[t] - v;
    if (i < n) {
        offs[i] = excl;
        float wdeg = (float)(unsigned)(pk & 0xFFFFFFFFu) * FIXINV;
        dinv[i] = rsqrtf(wdeg + 1.0f);
    }
    if (i == n - 1) offs[n] = N_EDGES;
}

// Atomic-free CSR fill: pos = offs[dst] + seq[e]. 4-byte packed entry.
// (R1 lesson: do NOT fuse per-edge fp32 atomics here — +24 µs regression.)
__global__ void k_fill(const int* __restrict__ src, const int* __restrict__ dst,
                       const float* __restrict__ w, const float* __restrict__ dinv,
                       const int* __restrict__ offs, const int* __restrict__ seq,
                       unsigned* __restrict__ csr, int E) {
    int e = blockIdx.x * blockDim.x + threadIdx.x;
    if (e < E) {
        int s = src[e], d = dst[e];
        int pos = offs[d] + seq[e];
        float nm = dinv[s] * w[e] * dinv[d];
        unsigned q = (unsigned)(nm * Q16 + 0.5f);
        q = (q > 65535u) ? 65535u : q;
        csr[pos] = ((unsigned)s << 16) | q;
    }
}

// Layer-1 scalar aggregation, 4 lanes/node (quarter-wave) + shfl_xor combine.
// 784 blocks (vs 196 for 1 thr/node) — 4x the waves for latency hiding,
// 4 independent csr->x load chains per node.
__global__ void k_aggx(const int* __restrict__ offs, const unsigned* __restrict__ csr,
                       const float* __restrict__ x, const float* __restrict__ dinv,
                       float* __restrict__ aggx, int n) {
    int gid = blockIdx.x * blockDim.x + threadIdx.x;
    int node = gid >> 2;
    if (node >= n) return;
    int sub = gid & 3;
    float acc = 0.f;
    int e0 = offs[node], e1 = offs[node + 1];
    for (int j = e0 + sub; j < e1; j += 4) {
        unsigned e = csr[j];
        acc += x[e >> 16] * dec_nm(e);
    }
    acc += __shfl_xor(acc, 1);
    acc += __shfl_xor(acc, 2);
    if (sub == 0) {
        float di = dinv[node];
        aggx[node] = acc + x[node] * di * di;
    }
}

// ---------------------------------------------------------------------------
// Fused layer-1-matmul + layer-2 aggregation. 16 threads/node, 4 ch each.
__global__ void k_gather2F(const int* __restrict__ offs, const unsigned* __restrict__ csr,
                           const float* __restrict__ aggx, const float* __restrict__ dinv,
                           const float* __restrict__ kA1, const float* __restrict__ kB1,
                           float* __restrict__ agg2, int n) {
    int gid = blockIdx.x * blockDim.x + threadIdx.x;
    int node = gid >> 4;
    if (node >= n) return;
    int c4 = (gid & 15) * 4;
    float4 wa = *(const float4*)(kA1 + c4);
    float4 wb = *(const float4*)(kB1 + c4);
    float4 acc = {0.f, 0.f, 0.f, 0.f};
    int e0 = offs[node], e1 = offs[node + 1];
    int j = e0;
#define G2F_ACC(av, nmv) { \
        acc.x += nmv * fmaxf(av * wa.x + wb.x, 0.f); \
        acc.y += nmv * fmaxf(av * wa.y + wb.y, 0.f); \
        acc.z += nmv * fmaxf(av * wa.z + wb.z, 0.f); \
        acc.w += nmv * fmaxf(av * wa.w + wb.w, 0.f); }
    for (; j + 7 < e1; j += 8) {
        unsigned e_0 = csr[j];
        unsigned e_1 = csr[j + 1];
        unsigned e_2 = csr[j + 2];
        unsigned e_3 = csr[j + 3];
        unsigned e_4 = csr[j + 4];
        unsigned e_5 = csr[j + 5];
        unsigned e_6 = csr[j + 6];
        unsigned e_7 = csr[j + 7];
        float a0 = aggx[e_0 >> 16];
        float a1 = aggx[e_1 >> 16];
        float a2 = aggx[e_2 >> 16];
        float a3 = aggx[e_3 >> 16];
        float a4 = aggx[e_4 >> 16];
        float a5 = aggx[e_5 >> 16];
        float a6 = aggx[e_6 >> 16];
        float a7 = aggx[e_7 >> 16];
        G2F_ACC(a0, dec_nm(e_0)); G2F_ACC(a1, dec_nm(e_1));
        G2F_ACC(a2, dec_nm(e_2)); G2F_ACC(a3, dec_nm(e_3));
        G2F_ACC(a4, dec_nm(e_4)); G2F_ACC(a5, dec_nm(e_5));
        G2F_ACC(a6, dec_nm(e_6)); G2F_ACC(a7, dec_nm(e_7));
    }
    for (; j < e1; ++j) {
        unsigned e = csr[j];
        float a = aggx[e >> 16];
        G2F_ACC(a, dec_nm(e));
    }
    {
        float di = dinv[node];
        float d2 = di * di;
        float a = aggx[node];
        G2F_ACC(a, d2);
    }
#undef G2F_ACC
    *(float4*)(agg2 + (size_t)node * 64 + c4) = acc;
}

// ---------------------------------------------------------------------------
// Channel-sliced gather (layer 3) from the FP16 layer-2 output (sliced-16):
// slice table 1.6MB (per-XCD-L2-resident: slice==blockIdx&7 tracks XCD rr),
// 4 thr/node, 8B/thread, fp32 accumulation, 8-edge unroll.
__global__ void k_gatherS16(const int* __restrict__ offs, const unsigned* __restrict__ csr,
                            const __half* __restrict__ Hh, const float* __restrict__ dinv,
                            float* __restrict__ aggs, int n) {
    int slice = blockIdx.x & 7;
    int node = (blockIdx.x >> 3) * 64 + threadIdx.x / 4;
    if (node >= n) return;
    int cq = (threadIdx.x % 4) * 4;
    const __half* Hb = Hh + (size_t)slice * ((size_t)n * 16);
    float4 acc = {0.f, 0.f, 0.f, 0.f};
    int e0 = offs[node], e1 = offs[node + 1];
    int j = e0;
#define GS16_LOAD(ev, rawv) uint2 rawv = *(const uint2*)(Hb + (size_t)((ev) >> 16) * 16 + cq)
#define GS16_ACC(rawv, nmv) { \
        __half2 p0 = *(__half2*)&rawv.x; \
        __half2 p1 = *(__half2*)&rawv.y; \
        float2 f0 = __half22float2(p0); \
        float2 f1 = __half22float2(p1); \
        acc.x += f0.x * nmv; acc.y += f0.y * nmv; \
        acc.z += f1.x * nmv; acc.w += f1.y * nmv; }
    for (; j + 7 < e1; j += 8) {
        unsigned e_0 = csr[j];
        unsigned e_1 = csr[j + 1];
        unsigned e_2 = csr[j + 2];
        unsigned e_3 = csr[j + 3];
        unsigned e_4 = csr[j + 4];
        unsigned e_5 = csr[j + 5];
        unsigned e_6 = csr[j + 6];
        unsigned e_7 = csr[j + 7];
        GS16_LOAD(e_0, r0); GS16_LOAD(e_1, r1); GS16_LOAD(e_2, r2); GS16_LOAD(e_3, r3);
        GS16_LOAD(e_4, r4); GS16_LOAD(e_5, r5); GS16_LOAD(e_6, r6); GS16_LOAD(e_7, r7);
        GS16_ACC(r0, dec_nm(e_0)); GS16_ACC(r1, dec_nm(e_1));
        GS16_ACC(r2, dec_nm(e_2)); GS16_ACC(r3, dec_nm(e_3));
        GS16_ACC(r4, dec_nm(e_4)); GS16_ACC(r5, dec_nm(e_5));
        GS16_ACC(r6, dec_nm(e_6)); GS16_ACC(r7, dec_nm(e_7));
    }
    for (; j < e1; ++j) {
        unsigned e = csr[j];
        GS16_LOAD(e, rr);
        GS16_ACC(rr, dec_nm(e));
    }
    {
        float di = dinv[node];
        float d2 = di * di;
        GS16_LOAD((unsigned)node << 16, rs);
        GS16_ACC(rs, d2);
    }
#undef GS16_LOAD
#undef GS16_ACC
    *(float4*)(aggs + (size_t)slice * ((size_t)n * 16) + (size_t)node * 16 + cq) = acc;
}

// ---------------------------------------------------------------------------
// Register-tiled matmul: 32 nodes/block, x-tile AND W staged in LDS.
// k4/p loops pinned rolled (#pragma unroll 1) — r6/r8 spilled at 256 VGPR.
// MODE 0 (layer 2): write fp16 table only.
// MODE 1 (layer 3): residual from fp16 table; FUSED mean-pool — block-local
// segmented reduction (batch sorted -> 1-2 graph segments per 32-node tile)
// into LDS, then ~128 fp32 atomics per segment into sums[500][128].
// Kills the 25.6MB h write + 25.6MB poolfinal re-read.
template <int K, int S, int MODE>
__global__ __launch_bounds__(256) void k_mmT(
    const float* __restrict__ Xs, const float* __restrict__ W,
    const float* __restrict__ kA, const float* __restrict__ kB,
    const __half* __restrict__ resh, const int* __restrict__ batch,
    float* __restrict__ sums, __half* __restrict__ outh, int n) {
    constexpr int CS = K / S;
    constexpr int KP = K + 4;
    constexpr int KH = 64;
    constexpr int NPASS = K / KH;
    __shared__ float xl[32 * KP];
    __shared__ float wl[KH * 128];
    int base = blockIdx.x * 32;
    int tid = threadIdx.x;
    constexpr int TOT4 = 32 * K / 4;
    constexpr int SL4 = 32 * CS / 4;
    for (int i = tid; i < TOT4; i += 256) {
        int slice = i / SL4;
        int rem = i - slice * SL4;
        int nl = rem / (CS / 4);
        int off4 = (rem % (CS / 4)) * 4;
        int node = base + nl;
        float4 v = {0.f, 0.f, 0.f, 0.f};
        if (node < n)
            v = *(const float4*)(Xs + (size_t)slice * ((size_t)n * CS) + (size_t)node * CS + off4);
        *(float4*)(&xl[nl * KP + slice * CS + off4]) = v;
    }

    int ct = tid & 31;
    int ng = tid >> 5;
    int c4 = ct * 4;
    float4 acc[4];
#pragma unroll
    for (int i = 0; i < 4; ++i) acc[i] = make_float4(0.f, 0.f, 0.f, 0.f);

#pragma unroll 1
    for (int p = 0; p < NPASS; ++p) {
        if (p > 0) __syncthreads();
        {
            const float4* Wsrc = (const float4*)(W + (size_t)p * KH * 128);
            float4* wl4 = (float4*)wl;
#pragma unroll 1
            for (int i = tid; i < KH * 32; i += 256) wl4[i] = Wsrc[i];
        }
        __syncthreads();

#pragma unroll 1
        for (int k4 = 0; k4 < KH / 4; ++k4) {
            float4 wv0 = *(const float4*)(&wl[(k4 * 4 + 0) * 128 + c4]);
            float4 wv1 = *(const float4*)(&wl[(k4 * 4 + 1) * 128 + c4]);
            float4 wv2 = *(const float4*)(&wl[(k4 * 4 + 2) * 128 + c4]);
            float4 wv3 = *(const float4*)(&wl[(k4 * 4 + 3) * 128 + c4]);
#pragma unroll
            for (int i = 0; i < 4; ++i) {
                float4 xv = *(const float4*)(&xl[(ng * 4 + i) * KP + p * KH + k4 * 4]);
                acc[i].x += xv.x * wv0.x; acc[i].y += xv.x * wv0.y;
                acc[i].z += xv.x * wv0.z; acc[i].w += xv.x * wv0.w;
                acc[i].x += xv.y * wv1.x; acc[i].y += xv.y * wv1.y;
                acc[i].z += xv.y * wv1.z; acc[i].w += xv.y * wv1.w;
                acc[i].x += xv.z * wv2.x; acc[i].y += xv.z * wv2.y;
                acc[i].z += xv.z * wv2.z; acc[i].w += xv.z * wv2.w;
                acc[i].x += xv.w * wv3.x; acc[i].y += xv.w * wv3.y;
                acc[i].z += xv.w * wv3.z; acc[i].w += xv.w * wv3.w;
            }
        }
    }

    float4 ka = *(const float4*)(kA + c4);
    float4 kb = *(const float4*)(kB + c4);
    int bg[4];
#pragma unroll
    for (int i = 0; i < 4; ++i) {
        int node = base + ng * 4 + i;
        bg[i] = -1;
        if (node >= n) continue;
        float4 a = acc[i];
        float4 v;
        v.x = fmaxf(a.x * ka.x + kb.x, 0.f);
        v.y = fmaxf(a.y * ka.y + kb.y, 0.f);
        v.z = fmaxf(a.z * ka.z + kb.z, 0.f);
        v.w = fmaxf(a.w * ka.w + kb.w, 0.f);
        size_t slot = (size_t)(c4 >> 4) * ((size_t)n * 16) + (size_t)node * 16 + (c4 & 15);
        if (MODE == 0) {
            __half2 h01 = __floats2half2_rn(v.x, v.y);
            __half2 h23 = __floats2half2_rn(v.z, v.w);
            uint2 r;
            r.x = *(unsigned*)&h01;
            r.y = *(unsigned*)&h23;
            *(uint2*)(outh + slot) = r;
        } else {
            uint2 rr = *(const uint2*)(resh + slot);
            __half2 p0 = *(__half2*)&rr.x;
            __half2 p1 = *(__half2*)&rr.y;
            float2 f0 = __half22float2(p0);
            float2 f1 = __half22float2(p1);
            v.x += f0.x; v.y += f0.y; v.z += f1.x; v.w += f1.y;
            acc[i] = v;                 // keep final h for pooling
            bg[i] = batch[node];
        }
    }
    if (MODE == 1) {
        __shared__ float pred[8][128];
        int g0 = batch[base];
        int gl = batch[(base + 31 < n) ? (base + 31) : (n - 1)];
        for (int g = g0; g <= gl; ++g) {
            float4 s = make_float4(0.f, 0.f, 0.f, 0.f);
#pragma unroll
            for (int i = 0; i < 4; ++i) {
                if (bg[i] == g) {
                    s.x += acc[i].x; s.y += acc[i].y;
                    s.z += acc[i].z; s.w += acc[i].w;
                }
            }
            __syncthreads();            // pred reusable across g iterations
            *(float4*)(&pred[ng][c4]) = s;
            __syncthreads();
            if (ng < 4) {
                pred[ng][c4 + 0] += pred[ng + 4][c4 + 0];
                pred[ng][c4 + 1] += pred[ng + 4][c4 + 1];
                pred[ng][c4 + 2] += pred[ng + 4][c4 + 2];
                pred[ng][c4 + 3] += pred[ng + 4][c4 + 3];
            }
            __syncthreads();
            if (ng < 2) {
                pred[ng][c4 + 0] += pred[ng + 2][c4 + 0];
                pred[ng][c4 + 1] += pred[ng + 2][c4 + 1];
                pred[ng][c4 + 2] += pred[ng + 2][c4 + 2];
                pred[ng][c4 + 3] += pred[ng + 2][c4 + 3];
            }
            __syncthreads();
            if (ng == 0) {
                atomicAdd(&sums[g * 128 + c4 + 0], pred[0][c4 + 0] + pred[1][c4 + 0]);
                atomicAdd(&sums[g * 128 + c4 + 1], pred[0][c4 + 1] + pred[1][c4 + 1]);
                atomicAdd(&sums[g * 128 + c4 + 2], pred[0][c4 + 2] + pred[1][c4 + 2]);
                atomicAdd(&sums[g * 128 + c4 + 3], pred[0][c4 + 3] + pred[1][c4 + 3]);
            }
        }
    }
}

// ---------------------------------------------------------------------------
// Finalize: out[g] = dot(sums[g]/cnt[g], Wf) + bf. 256KB read — trivial.
__global__ __launch_bounds__(128) void k_final(
    const float* __restrict__ sums, const int* __restrict__ goffs,
    const float* __restrict__ Wf, const float* __restrict__ bf,
    float* __restrict__ out) {
    int g = blockIdx.x;
    int t = threadIdx.x;
    float v = sums[g * 128 + t] * Wf[t];
    for (int o = 32; o > 0; o >>= 1) v += __shfl_down(v, o);
    __shared__ float r[2];
    if (t == 0) r[0] = v;
    if (t == 64) r[1] = v;
    __syncthreads();
    if (t == 0) {
        int cnt = goffs[g + 1] - goffs[g];
        out[g] = (r[0] + r[1]) / fmaxf((float)cnt, 1.f) + bf[0];
    }
}

// ---------------------------------------------------------------------------
extern "C" void kernel_launch(void* const* d_in, const int* in_sizes, int n_in,
                              void* d_out, int out_size, void* d_ws, size_t ws_size,
                              hipStream_t stream) {
    const float* x     = (const float*)d_in[0];
    const int*   ei    = (const int*)d_in[1];
    const int*   src   = ei;
    const int*   dst   = ei + N_EDGES;
    const float* w     = (const float*)d_in[2];
    const int*   batch = (const int*)d_in[3];
    const float* W1 = (const float*)d_in[4];
    const float* b1 = (const float*)d_in[5];
    const float* W2 = (const float*)d_in[6];
    const float* b2 = (const float*)d_in[7];
    const float* W3 = (const float*)d_in[8];
    const float* b3 = (const float*)d_in[9];
    const float* Wf = (const float*)d_in[10];
    const float* bf = (const float*)d_in[11];
    const float* g1 = (const float*)d_in[12];
    const float* be1 = (const float*)d_in[13];
    const float* m1 = (const float*)d_in[14];
    const float* v1 = (const float*)d_in[15];
    const float* g2 = (const float*)d_in[16];
    const float* be2 = (const float*)d_in[17];
    const float* m2 = (const float*)d_in[18];
    const float* v2 = (const float*)d_in[19];
    const float* g3 = (const float*)d_in[20];
    const float* be3 = (const float*)d_in[21];
    const float* m3 = (const float*)d_in[22];
    const float* v3 = (const float*)d_in[23];

    float* out = (float*)d_out;

    // Workspace layout
    float* ws    = (float*)d_ws;
    float* buf2  = ws;                                    // N*128 fp32: agg2 then agg3s
    float* agg2  = buf2;
    unsigned* csr = (unsigned*)(buf2 + (size_t)N_NODES * 128); // E uint
    unsigned long long* packed = (unsigned long long*)(csr + N_EDGES); // N ull
    float* sums  = (float*)(packed + N_NODES);            // G*128 (memset with packed)
    int*   seq   = (int*)(sums + N_GRAPHS * 128);         // E
    float* dinv  = (float*)(seq + N_EDGES);               // N
    float* aggx  = dinv + N_NODES;                        // N
    float* kA1   = aggx + N_NODES;                        // 64
    float* kB1   = kA1 + 64;                              // 64
    float* kA2   = kB1 + 64;                              // 128
    float* kB2   = kA2 + 128;                             // 128
    float* kA3   = kB2 + 128;                             // 128
    float* kB3   = kA3 + 128;                             // 128
    int*   offs  = (int*)(kB3 + 128);                     // N+1
    int*   bsum  = offs + N_NODES + 1;                    // SCAN_NB
    int*   bpre  = bsum + SCAN_NB;                        // SCAN_NB
    int*   goffs = bpre + SCAN_NB;                        // G+1 (+pad)
    __half* out2h = (__half*)(goffs + 505);               // N*128 fp16 (12.8 MB)

    const int BS = 256;
    auto nb = [](long n) { return (int)((n + 255) / 256); };

    // zero packed + sums in one call (adjacent in ws)
    hipMemsetAsync(packed, 0,
                   N_NODES * sizeof(unsigned long long) + (size_t)N_GRAPHS * 128 * sizeof(float),
                   stream);

    // --- CSR build + degree norm (+goffs precompute overlapped in scan1) ---
    k_degcnt<<<nb(N_EDGES), BS, 0, stream>>>(dst, w, packed, seq, N_EDGES);
    k_scan1<<<SCAN_NB, 256, 0, stream>>>(packed, bsum, batch, goffs, N_NODES);
    k_scan2_bnprep<<<1, 320, 0, stream>>>(bsum, bpre, SCAN_NB,
                                          W1, b1, g1, be1, m1, v1, b2, g2, be2, m2, v2,
                                          b3, g3, be3, m3, v3,
                                          kA1, kB1, kA2, kB2, kA3, kB3);
    k_scan3<<<SCAN_NB, 256, 0, stream>>>(packed, bpre, offs, dinv, N_NODES);
    k_fill<<<nb(N_EDGES), BS, 0, stream>>>(src, dst, w, dinv, offs, seq, csr, N_EDGES);

    // --- Layer 1 aggregate (4 lanes/node) ---
    k_aggx<<<nb((long)N_NODES * 4), BS, 0, stream>>>(offs, csr, x, dinv, aggx, N_NODES);

    // --- Layer 2: fused L1-matmul + aggregate, then matmul -> fp16 ---
    k_gather2F<<<nb((long)N_NODES * 16), BS, 0, stream>>>(
        offs, csr, aggx, dinv, kA1, kB1, agg2, N_NODES);
    k_mmT<64, 1, 0><<<(N_NODES + 31) / 32, BS, 0, stream>>>(
        agg2, W2, kA2, kB2, nullptr, nullptr, nullptr, out2h, N_NODES);

    // --- Layer 3: sliced aggregate from fp16 table, matmul + res + fused pool ---
    k_gatherS16<<<8 * ((N_NODES + 63) / 64), BS, 0, stream>>>(
        offs, csr, out2h, dinv, buf2, N_NODES);
    k_mmT<128, 8, 1><<<(N_NODES + 31) / 32, BS, 0, stream>>>(
        buf2, W3, kA3, kB3, out2h, batch, sums, nullptr, N_NODES);

    // --- finalize: tiny dot-product over sums ---
    k_final<<<N_GRAPHS, 128, 0, stream>>>(sums, goffs, Wf, bf, out);
}